// Round 2
// baseline (173.385 us; speedup 1.0000x reference)
//
#include <hip/hip_runtime.h>
#include <hip/hip_bf16.h>

typedef unsigned short u16;
typedef unsigned int u32;
typedef u16 u16x4 __attribute__((ext_vector_type(4)));
typedef u16 u16x8 __attribute__((ext_vector_type(8)));
typedef __bf16 bf16x8 __attribute__((ext_vector_type(8)));
typedef float f32x4 __attribute__((ext_vector_type(4)));

#define USER_N 1000
#define CATE_N 1400
#define FEAT_N 128
#define B_N 8192
#define CAP 64     // max rows per category list (Binom(8192,1/1400) tail-safe)

__device__ __forceinline__ float b2f(u16 u) {
    union { u32 i; float f; } v; v.i = ((u32)u) << 16; return v.f;
}
__device__ __forceinline__ u16 f2b(float f) {
    union { float f; u32 i; } v; v.f = f;
    u32 x = v.i;
    u32 r = (x + 0x7fffu + ((x >> 16) & 1u)) >> 16;
    return (u16)r;
}
__device__ __forceinline__ f32x4 ld4u(const float* p) {   // 4B-aligned-safe
    f32x4 v; __builtin_memcpy(&v, p, 16); return v;
}
__device__ __forceinline__ bf16x8 cvt8(f32x4 a, f32x4 b) {
    u16x8 r = {f2b(a.x), f2b(a.y), f2b(a.z), f2b(a.w),
               f2b(b.x), f2b(b.y), f2b(b.z), f2b(b.w)};
    return __builtin_bit_cast(bf16x8, r);
}
// X in MFMA A-fragment order: row b, col k ->
//   XA[(b>>4)*4096 + (k>>3)*128 + (b&15)*8 + (k&7)]
__device__ __forceinline__ size_t xa_addr(int b, int k) {
    return (size_t)(b >> 4) * 4096 + (size_t)(k >> 3) * 128 + (b & 15) * 8 + (k & 7);
}

// ---------------- Kernel 1: p0 (MFMA) + cat chain + WB/t pack -------------
// 384 blocks x 256 thr.
//  blocks 0..255  : 32 rows each. 4 waves: (w>>1)=m-tile, (w&1)=nt-half.
//                   feat read direct, fc0_w converted in-wave (L2-hot).
//                   Then wave-local cat chain (8 rows/wave) + XA head.
//  blocks 256..383: WB (usr_w/ubias B-frags) + t[u].
__global__ __launch_bounds__(256) void prep_kernel(
    const float* __restrict__ feat, const int* __restrict__ fcat,
    const float* __restrict__ cate_w, const float* __restrict__ cmat_w,
    const float* __restrict__ cbias_w, const float* __restrict__ fc0_w,
    const float* __restrict__ fc0_b,
    const float* __restrict__ usr_w, const float* __restrict__ ubias_w,
    u16* __restrict__ WB, float* __restrict__ t,
    u16* __restrict__ p0Gb, u16* __restrict__ XA)
{
    const int bx = blockIdx.x;
    const int tid = threadIdx.x;

    if (bx >= 256) {
        // ---- WB pack + t
        const int gid = (bx - 256) * 256 + tid;   // 0..32767
        const int u = gid >> 5;                   // 0..1023
        const int l = gid & 31;
        float part = 0.f;
        u16x4 wa = {0, 0, 0, 0}, wb = {0, 0, 0, 0};
        if (u < USER_N) {
            f32x4 a4 = *(const f32x4*)&usr_w[u * 128 + l * 4];
            f32x4 b4 = *(const f32x4*)&ubias_w[u * 128 + l * 4];
            wa = (u16x4){f2b(a4.x), f2b(a4.y), f2b(a4.z), f2b(a4.w)};
            wb = (u16x4){f2b(b4.x), f2b(b4.y), f2b(b4.z), f2b(b4.w)};
            part = a4.x * b4.x + a4.y * b4.y + a4.z * b4.z + a4.w * b4.w;
        }
        const int nb = u >> 4, lm = u & 15;
        const int ks = l >> 3, quad = (l >> 1) & 3, j0 = (l & 1) * 4;
        *(u16x4*)&WB[(size_t)(nb * 8 + ks) * 512 + quad * 128 + lm * 8 + j0] = wa;
        *(u16x4*)&WB[(size_t)(nb * 8 + 4 + ks) * 512 + quad * 128 + lm * 8 + j0] = wb;
        part += __shfl_xor(part, 16, 32);
        part += __shfl_xor(part, 8, 32);
        part += __shfl_xor(part, 4, 32);
        part += __shfl_xor(part, 2, 32);
        part += __shfl_xor(part, 1, 32);
        if (l == 0 && u < USER_N) t[u] = part;
        return;
    }

    const int w = tid >> 6, lane = tid & 63;
    const int lm = lane & 15, quad = lane >> 4;
    const int b0 = bx * 32;

    // ---- p0: wave -> (m-tile, nt-half)
    const int mt = bx * 2 + (w >> 1);
    const int nth = w & 1;
    bf16x8 a[4];
    const float* frw = feat + (size_t)(mt * 16 + lm) * 128 + quad * 8;
    #pragma unroll
    for (int ks = 0; ks < 4; ++ks)
        a[ks] = cvt8(*(const f32x4*)(frw + ks * 32),
                     *(const f32x4*)(frw + ks * 32 + 4));

    #pragma unroll
    for (int nt3 = 0; nt3 < 3; ++nt3) {
        const int nt = nth * 3 + nt3;
        const int i = nt * 16 + lm;              // output col (n)
        const bool v = (i < 95);
        const float* br = fc0_w + (size_t)(v ? i : 0) * 128 + quad * 8;
        f32x4 acc = {0.f, 0.f, 0.f, 0.f};
        #pragma unroll
        for (int ks = 0; ks < 4; ++ks) {
            f32x4 lo = {0,0,0,0}, hi = {0,0,0,0};
            if (v) { lo = *(const f32x4*)(br + ks * 32);
                     hi = *(const f32x4*)(br + ks * 32 + 4); }
            acc = __builtin_amdgcn_mfma_f32_16x16x32_bf16(a[ks], cvt8(lo, hi),
                                                          acc, 0, 0, 0);
        }
        const float bias = v ? fc0_b[i] : 0.f;
        #pragma unroll
        for (int r = 0; r < 4; ++r) {
            int row = mt * 16 + quad * 4 + r;
            p0Gb[(size_t)row * 96 + i] = v ? f2b(acc[r] + bias) : (u16)0;
        }
    }

    // ---- cat chain: wave w owns rows b0+w*8 .. +7; lane = (oct<<3)|r8
    __shared__ float chS[4][8][34];
    const int r8 = lane & 7, oct = lane >> 3;
    const int row = b0 + w * 8 + r8;
    const int c0 = fcat[row * 3 + 0];
    const int c1 = fcat[row * 3 + 1];
    const int c2 = fcat[row * 3 + 2];

    #pragma unroll
    for (int dd = 0; dd < 2; ++dd) {
        int d = oct + dd * 8;
        if (d < 11) chS[w][r8][d] = cate_w[c0 * 11 + d];
    }
    asm volatile("s_waitcnt lgkmcnt(0)" ::: "memory");
    __builtin_amdgcn_sched_barrier(0);

    float st[2];
    #pragma unroll
    for (int dd = 0; dd < 2; ++dd) {
        int d = oct + dd * 8;
        st[dd] = 0.f;
        if (d < 11) {
            float acc = cbias_w[c1 * 11 + d];
            const float* cm = cmat_w + (size_t)c1 * 121 + d * 11;
            #pragma unroll
            for (int j = 0; j < 11; ++j) acc += cm[j] * chS[w][r8][j];
            st[dd] = acc;
        }
    }
    #pragma unroll
    for (int dd = 0; dd < 2; ++dd) {
        int d = oct + dd * 8;
        if (d < 11) chS[w][r8][11 + d] = st[dd];
    }
    asm volatile("s_waitcnt lgkmcnt(0)" ::: "memory");
    __builtin_amdgcn_sched_barrier(0);

    #pragma unroll
    for (int dd = 0; dd < 2; ++dd) {
        int d = oct + dd * 8;
        st[dd] = 0.f;
        if (d < 11) {
            float acc = cbias_w[c2 * 11 + d];
            const float* cm = cmat_w + (size_t)c2 * 121 + d * 11;
            #pragma unroll
            for (int j = 0; j < 11; ++j) acc += cm[j] * chS[w][r8][11 + j];
            st[dd] = acc;
        }
    }
    #pragma unroll
    for (int dd = 0; dd < 2; ++dd) {
        int d = oct + dd * 8;
        if (d < 11) chS[w][r8][22 + d] = st[dd];
    }
    asm volatile("s_waitcnt lgkmcnt(0)" ::: "memory");
    __builtin_amdgcn_sched_barrier(0);

    // X cols 0..32 (cat1|cat2|cat3) and zeros at 128..160
    for (int idx = lane; idx < 8 * 33; idx += 64) {
        int r2 = idx / 33, cc = idx - r2 * 33;
        int bb = b0 + w * 8 + r2;
        XA[xa_addr(bb, cc)] = f2b(chS[w][r2][cc]);
        XA[xa_addr(bb, 128 + cc)] = 0;
    }
}

// ---------------- Kernel 2: per-category itmq via MFMA, self-binning ------
// 1400 blocks x 128 thr. B-frag raw loads issued first; fcat scan (L2-hot)
// builds the row list in LDS under the load latency. No counts/bins pass.
__global__ __launch_bounds__(128) void itmq_kernel(
    const float* __restrict__ cvismat_w, const float* __restrict__ cvisbias_w,
    const float* __restrict__ cbiasb_w, const int* __restrict__ fcat,
    const u16* __restrict__ p0Gb,
    u16* __restrict__ XA, float* __restrict__ s_out)
{
    const int c = blockIdx.x;
    const int tid = threadIdx.x;
    const int wave = tid >> 6, lane = tid & 63;
    const int lm = lane & 15, quad = lane >> 4;

    __shared__ float qS[16 * 96];
    __shared__ float cvbS[96], cbbS[96];
    __shared__ u16   cbb16S[96];
    __shared__ int   rlist[CAP];
    __shared__ int   nS;

    if (tid == 0) nS = 0;
    if (tid < 96) cvbS[tid] = (tid < 95) ? cvisbias_w[c * 95 + tid] : 0.f;
    if (tid >= 32) {
        int k = tid - 32;                        // 0..95
        float v = (k < 95) ? cbiasb_w[c * 95 + k] : 0.f;
        cbbS[k] = v;
        cbb16S[k] = f2b(v);
    }

    // ---- issue B-frag raw loads (biggest latency) before the scan
    f32x4 rawL[3][3], rawH[3][3];
    #pragma unroll
    for (int tnt = 0; tnt < 3; ++tnt) {
        const int i = (wave * 3 + tnt) * 16 + lm;  // output n index
        const bool v = (i < 95);
        const float* br = cvismat_w + (size_t)c * 9025 + (size_t)(v ? i : 0) * 95;
        #pragma unroll
        for (int ks = 0; ks < 3; ++ks) {
            f32x4 lo = {0,0,0,0}, hi = {0,0,0,0};
            if (v) {
                if (ks < 2 || quad < 3) {
                    lo = ld4u(br + ks * 32 + quad * 8);
                    hi = ld4u(br + ks * 32 + quad * 8 + 4);
                } else {                          // j = 88..95 (95 = pad)
                    lo = ld4u(br + 88);
                    hi.x = br[92]; hi.y = br[93]; hi.z = br[94]; hi.w = 0.f;
                }
            }
            rawL[tnt][ks] = lo; rawH[tnt][ks] = hi;
        }
    }

    // ---- self-bin: scan fcat[:,2] for category c (overlaps load latency)
    __syncthreads();                             // nS init visible
    #pragma unroll 4
    for (int it = 0; it < B_N / 128; ++it) {
        int r = it * 128 + tid;
        if (fcat[r * 3 + 2] == c) {
            int sl = atomicAdd(&nS, 1);
            if (sl < CAP) rlist[sl] = r;
        }
    }
    __syncthreads();
    int n = nS < CAP ? nS : CAP;
    if (n <= 0) return;

    // ---- convert B-frags
    bf16x8 bfr[3][3];
    #pragma unroll
    for (int tnt = 0; tnt < 3; ++tnt)
        #pragma unroll
        for (int ks = 0; ks < 3; ++ks)
            bfr[tnt][ks] = cvt8(rawL[tnt][ks], rawH[tnt][ks]);

    for (int m0 = 0; m0 < n; m0 += 16) {
        // A-frags: gathered p0Gb rows (bf16, col 95 pre-zeroed)
        const int am = m0 + lm;
        const int ab = rlist[am < n ? am : 0];
        const u16* pr = p0Gb + (size_t)ab * 96 + quad * 8;
        bf16x8 a[3];
        #pragma unroll
        for (int ks = 0; ks < 3; ++ks)
            a[ks] = __builtin_bit_cast(bf16x8, *(const u16x8*)(pr + ks * 32));
        f32x4 acc[3] = {{0,0,0,0}, {0,0,0,0}, {0,0,0,0}};
        #pragma unroll
        for (int tnt = 0; tnt < 3; ++tnt)
            #pragma unroll
            for (int ks = 0; ks < 3; ++ks)
                acc[tnt] = __builtin_amdgcn_mfma_f32_16x16x32_bf16(
                    a[ks], bfr[tnt][ks], acc[tnt], 0, 0, 0);

        __syncthreads();                 // prior chunk's qS consumed
        #pragma unroll
        for (int tnt = 0; tnt < 3; ++tnt) {
            const int i = (wave * 3 + tnt) * 16 + lm;
            #pragma unroll
            for (int r = 0; r < 4; ++r)
                qS[(quad * 4 + r) * 96 + i] = acc[tnt][r] + cvbS[i];
        }
        __syncthreads();

        // s[b] = dot(itmq, cbb): 8 lanes/row
        {
            const int rr = tid >> 3, q8 = tid & 7;
            float p = 0.f;
            if (m0 + rr < n)
                for (int i = q8; i < 95; i += 8) p += qS[rr * 96 + i] * cbbS[i];
            p += __shfl_xor(p, 4, 8);
            p += __shfl_xor(p, 2, 8);
            p += __shfl_xor(p, 1, 8);
            if (q8 == 0 && m0 + rr < n) s_out[rlist[m0 + rr]] = p;
        }
        // X tail: cols 33..127 itmq, 161..255 cbb
        const int nv = min(16, n - m0);
        for (int idx = tid; idx < nv * 95; idx += 128) {
            int r2 = idx / 95;
            int col = idx - r2 * 95;
            int bb = rlist[m0 + r2];
            XA[xa_addr(bb, 33 + col)] = f2b(qS[r2 * 96 + col]);
            XA[xa_addr(bb, 161 + col)] = cbb16S[col];
        }
    }
}

// ---------------- Kernel 3: GEMM out = X @ W^T + s + t --------------------
// 1024 blocks x 256 thr. bid&7 = user-slice (g) -> each XCD keeps its
// 64 KB WB slice L2-hot and streams XA once. Wave = 16 rows x 128 users.
__global__ __launch_bounds__(256) void gemm_kernel(
    const u16* __restrict__ XA, const u16* __restrict__ WB,
    const float* __restrict__ s, const float* __restrict__ t,
    float* __restrict__ out)
{
    const int tid = threadIdx.x;
    const int wave = tid >> 6;
    const int lane = tid & 63;
    const int lm = lane & 15;
    const int quad = lane >> 4;
    const int lofs = quad * 128 + lm * 8;

    const int bid = blockIdx.x;
    const int g = bid & 7;               // users g*128 .. g*128+127
    const int p = bid >> 3;              // 0..127
    const int mb = p * 4 + wave;         // m-tile 0..511
    const u16* abase = XA + (size_t)mb * 4096 + lofs;
    const u16* bbase = WB + (size_t)(g * 8) * 4096 + lofs;

    f32x4 acc[8];
    #pragma unroll
    for (int j = 0; j < 8; ++j) acc[j] = (f32x4){0.f, 0.f, 0.f, 0.f};

    #pragma unroll 2
    for (int ks = 0; ks < 8; ++ks) {
        const int o = ks * 512;
        bf16x8 a = __builtin_bit_cast(bf16x8, *(const u16x8*)(abase + o));
        #pragma unroll
        for (int j = 0; j < 8; ++j) {
            bf16x8 b = __builtin_bit_cast(bf16x8,
                *(const u16x8*)(bbase + (size_t)j * 4096 + o));
            acc[j] = __builtin_amdgcn_mfma_f32_16x16x32_bf16(a, b, acc[j], 0, 0, 0);
        }
    }

    const int m0 = mb * 16;
    float sv[4];
    #pragma unroll
    for (int r = 0; r < 4; ++r) sv[r] = s[m0 + quad * 4 + r];

    #pragma unroll
    for (int j = 0; j < 8; ++j) {
        int u = g * 128 + j * 16 + lm;
        if (u < USER_N) {
            float tv = t[u];
            #pragma unroll
            for (int r = 0; r < 4; ++r) {
                int ob = m0 + quad * 4 + r;
                out[(size_t)ob * USER_N + u] = acc[j][r] + sv[r] + tv;
            }
        }
    }
}

extern "C" void kernel_launch(void* const* d_in, const int* in_sizes, int n_in,
                              void* d_out, int out_size, void* d_ws, size_t ws_size,
                              hipStream_t stream) {
    const float* feat      = (const float*)d_in[0];
    const int*   fcat      = (const int*)d_in[1];
    // d_in[2] fusr, d_in[3] fitm, d_in[4] flg: unused (flg==1 branch)
    const float* usr_w     = (const float*)d_in[5];
    const float* cate_w    = (const float*)d_in[6];
    const float* cmat_w    = (const float*)d_in[7];
    const float* cbias_w   = (const float*)d_in[8];
    const float* ubias_w   = (const float*)d_in[9];
    const float* cbiasb_w  = (const float*)d_in[10];
    const float* fc0_w     = (const float*)d_in[11];
    const float* fc0_b     = (const float*)d_in[12];
    const float* cvismat_w = (const float*)d_in[13];
    const float* cvisbias_w= (const float*)d_in[14];
    float* out = (float*)d_out;

    char* ws = (char*)d_ws;
    u16*   XA     = (u16*)(ws);                 // 4,194,304 B
    u16*   WB     = (u16*)(ws + 4194304);       //   524,288 B
    float* s      = (float*)(ws + 4718592);     //    32,768 B
    float* t      = (float*)(ws + 4751360);     //     4,096 B
    u16*   p0Gb   = (u16*)(ws + 4755456);       // 1,572,864 B (bf16 p0)

    prep_kernel<<<384, 256, 0, stream>>>(feat, fcat, cate_w, cmat_w, cbias_w,
                                         fc0_w, fc0_b, usr_w, ubias_w,
                                         WB, t, p0Gb, XA);
    itmq_kernel<<<CATE_N, 128, 0, stream>>>(cvismat_w, cvisbias_w, cbiasb_w,
                                            fcat, p0Gb, XA, s);
    gemm_kernel<<<1024, 256, 0, stream>>>(XA, WB, s, t, out);
}

// Round 3
// 160.963 us; speedup vs baseline: 1.0772x; 1.0772x over previous
//
#include <hip/hip_runtime.h>
#include <hip/hip_bf16.h>

typedef unsigned short u16;
typedef unsigned int u32;
typedef u16 u16x4 __attribute__((ext_vector_type(4)));
typedef u16 u16x8 __attribute__((ext_vector_type(8)));
typedef __bf16 bf16x8 __attribute__((ext_vector_type(8)));
typedef float f32x4 __attribute__((ext_vector_type(4)));

#define USER_N 1000
#define CATE_N 1400
#define FEAT_N 128
#define B_N 8192
#define CAP 64     // max rows per category bin (Binom(8192,1/1400) tail-safe)

__device__ __forceinline__ float b2f(u16 u) {
    union { u32 i; float f; } v; v.i = ((u32)u) << 16; return v.f;
}
__device__ __forceinline__ u16 f2b(float f) {
    union { float f; u32 i; } v; v.f = f;
    u32 x = v.i;
    u32 r = (x + 0x7fffu + ((x >> 16) & 1u)) >> 16;
    return (u16)r;
}
__device__ __forceinline__ f32x4 ld4u(const float* p) {   // 4B-aligned-safe
    f32x4 v; __builtin_memcpy(&v, p, 16); return v;
}
__device__ __forceinline__ bf16x8 cvt8(f32x4 a, f32x4 b) {
    u16x8 r = {f2b(a.x), f2b(a.y), f2b(a.z), f2b(a.w),
               f2b(b.x), f2b(b.y), f2b(b.z), f2b(b.w)};
    return __builtin_bit_cast(bf16x8, r);
}
// X in MFMA A-fragment order: row b, col k ->
//   XA[(b>>4)*4096 + (k>>3)*128 + (b&15)*8 + (k&7)]
__device__ __forceinline__ size_t xa_addr(int b, int k) {
    return (size_t)(b >> 4) * 4096 + (size_t)(k >> 3) * 128 + (b & 15) * 8 + (k & 7);
}

// ---------------- Kernel 1: pack WB (B-frag) + t[u] + zero counts ---------
__global__ __launch_bounds__(256) void pack_kernel(
    const float* __restrict__ usr_w, const float* __restrict__ ubias_w,
    u16* __restrict__ WB, float* __restrict__ t, int* __restrict__ counts)
{
    if (blockIdx.x == 0) {
        for (int i = threadIdx.x; i < CATE_N; i += 256) counts[i] = 0;
    }
    const int gid = blockIdx.x * 256 + threadIdx.x;
    const int u = gid >> 5;
    const int l = gid & 31;
    if (u >= 1024) return;
    float part = 0.f;
    u16x4 wa = {0, 0, 0, 0}, wb = {0, 0, 0, 0};
    if (u < USER_N) {
        f32x4 a4 = *(const f32x4*)&usr_w[u * 128 + l * 4];
        f32x4 b4 = *(const f32x4*)&ubias_w[u * 128 + l * 4];
        wa = (u16x4){f2b(a4.x), f2b(a4.y), f2b(a4.z), f2b(a4.w)};
        wb = (u16x4){f2b(b4.x), f2b(b4.y), f2b(b4.z), f2b(b4.w)};
        part = a4.x * b4.x + a4.y * b4.y + a4.z * b4.z + a4.w * b4.w;
    }
    const int nb = u >> 4, lm = u & 15;
    const int ks = l >> 3, quad = (l >> 1) & 3, j0 = (l & 1) * 4;
    *(u16x4*)&WB[(size_t)(nb * 8 + ks) * 512 + quad * 128 + lm * 8 + j0] = wa;
    *(u16x4*)&WB[(size_t)(nb * 8 + 4 + ks) * 512 + quad * 128 + lm * 8 + j0] = wb;
    part += __shfl_xor(part, 16, 32);
    part += __shfl_xor(part, 8, 32);
    part += __shfl_xor(part, 4, 32);
    part += __shfl_xor(part, 2, 32);
    part += __shfl_xor(part, 1, 32);
    if (l == 0) t[u] = part;
}

// ---------------- Kernel 2: bin rows by c2 --------------------------------
__global__ __launch_bounds__(256) void bin_kernel(
    const int* __restrict__ fcat, int* __restrict__ counts,
    int* __restrict__ bins)
{
    const int gid = blockIdx.x * 256 + threadIdx.x;
    if (gid < B_N) {
        int c2 = fcat[gid * 3 + 2];
        int slot = atomicAdd(&counts[c2], 1);
        if (slot < CAP) bins[c2 * CAP + slot] = gid;
    }
}

// ---------------- Kernel 3: p0 via MFMA + cat chain -----------------------
// 256 blocks x 128 thr (2 waves). Wave = one 16-row m-tile.
// p0[16x96] = feat[16x128] @ fc0_w^T (bf16 MFMA, B-frags direct from fc0_w
// rows). Then cat1/2/3 chain and X cols 0..32 / zeros 128..160.
__global__ __launch_bounds__(128) void p0chain_kernel(
    const float* __restrict__ feat, const int* __restrict__ fcat,
    const float* __restrict__ cate_w, const float* __restrict__ cmat_w,
    const float* __restrict__ cbias_w, const float* __restrict__ fc0_w,
    const float* __restrict__ fc0_b,
    float* __restrict__ p0G, u16* __restrict__ XA)
{
    const int tid = threadIdx.x;
    const int wave = tid >> 6, lane = tid & 63;
    const int lm = lane & 15, quad = lane >> 4;
    const int mt = blockIdx.x * 2 + wave;       // 0..511
    const int b0 = mt * 16;

    // A-frags (feat rows, aligned)
    bf16x8 a[4];
    const float* frw = feat + (size_t)(b0 + lm) * 128 + quad * 8;
    #pragma unroll
    for (int ks = 0; ks < 4; ++ks)
        a[ks] = cvt8(*(const f32x4*)(frw + ks * 32),
                     *(const f32x4*)(frw + ks * 32 + 4));

    #pragma unroll
    for (int nt = 0; nt < 6; ++nt) {
        const int i = nt * 16 + lm;              // output col (n)
        const bool v = (i < 95);
        const float* br = fc0_w + (size_t)(v ? i : 0) * 128 + quad * 8;
        f32x4 acc = {0.f, 0.f, 0.f, 0.f};
        #pragma unroll
        for (int ks = 0; ks < 4; ++ks) {
            f32x4 lo = {0,0,0,0}, hi = {0,0,0,0};
            if (v) { lo = *(const f32x4*)(br + ks * 32);
                     hi = *(const f32x4*)(br + ks * 32 + 4); }
            acc = __builtin_amdgcn_mfma_f32_16x16x32_bf16(a[ks], cvt8(lo, hi),
                                                          acc, 0, 0, 0);
        }
        const float bias = v ? fc0_b[i] : 0.f;
        #pragma unroll
        for (int r = 0; r < 4; ++r) {
            int row = b0 + quad * 4 + r;         // D: row = quad*4+reg
            p0G[(size_t)row * 96 + i] = v ? (acc[r] + bias) : 0.f;  // col95 pad=0
        }
    }

    // ---- cat chain: lane r=lm owns row b0+r; quad covers dims {q,q+4,q+8}
    __shared__ float chainS[2][16][36];
    const int r = lm;
    const int bq = b0 + r;
    const int c0 = fcat[bq * 3 + 0], c1 = fcat[bq * 3 + 1], c2 = fcat[bq * 3 + 2];

    #pragma unroll
    for (int dd = 0; dd < 3; ++dd) {
        int d = quad + dd * 4;
        if (d < 11) chainS[wave][r][d] = cate_w[c0 * 11 + d];
    }
    __syncthreads();
    float st[3];
    #pragma unroll
    for (int dd = 0; dd < 3; ++dd) {
        int d = quad + dd * 4;
        if (d < 11) {
            float acc = cbias_w[c1 * 11 + d];
            #pragma unroll
            for (int j = 0; j < 11; ++j)
                acc += cmat_w[c1 * 121 + d * 11 + j] * chainS[wave][r][j];
            st[dd] = acc;
        }
    }
    #pragma unroll
    for (int dd = 0; dd < 3; ++dd) {
        int d = quad + dd * 4;
        if (d < 11) chainS[wave][r][11 + d] = st[dd];
    }
    __syncthreads();
    #pragma unroll
    for (int dd = 0; dd < 3; ++dd) {
        int d = quad + dd * 4;
        if (d < 11) {
            float acc = cbias_w[c2 * 11 + d];
            #pragma unroll
            for (int j = 0; j < 11; ++j)
                acc += cmat_w[c2 * 121 + d * 11 + j] * chainS[wave][r][11 + j];
            st[dd] = acc;
        }
    }
    #pragma unroll
    for (int dd = 0; dd < 3; ++dd) {
        int d = quad + dd * 4;
        if (d < 11) chainS[wave][r][22 + d] = st[dd];
    }
    __syncthreads();
    for (int idx = lane; idx < 16 * 33; idx += 64) {
        int r2 = idx / 33, cc = idx - r2 * 33;
        int bb = b0 + r2;
        XA[xa_addr(bb, cc)] = f2b(chainS[wave][r2][cc]);
        XA[xa_addr(bb, 128 + cc)] = 0;
    }
}

// ---------------- Kernel 4: per-category itmq via MFMA --------------------
// 1400 blocks x 128 thr. B-frags = cvismat rows direct from global (read
// once, streaming). A = gathered p0G rows (bf16). M=16/tile, K=96, N=96.
__global__ __launch_bounds__(128) void itmq_kernel(
    const float* __restrict__ cvismat_w, const float* __restrict__ cvisbias_w,
    const float* __restrict__ cbiasb_w,
    const int* __restrict__ counts, const int* __restrict__ bins,
    const float* __restrict__ p0G,
    u16* __restrict__ XA, float* __restrict__ s_out)
{
    const int c = blockIdx.x;
    int n = counts[c];
    if (n <= 0) return;
    if (n > CAP) n = CAP;
    const int tid = threadIdx.x;
    const int wave = tid >> 6, lane = tid & 63;
    const int lm = lane & 15, quad = lane >> 4;

    __shared__ float qS[16 * 96];
    __shared__ float cvbS[96], cbbS[96];
    __shared__ u16   cbb16S[96];
    __shared__ int   brS[16];

    if (tid < 96) cvbS[tid] = (tid < 95) ? cvisbias_w[c * 95 + tid] : 0.f;
    if (tid >= 32) {
        int k = tid - 32;                        // 0..95
        float v = (k < 95) ? cbiasb_w[c * 95 + k] : 0.f;
        cbbS[k] = v;
        cbb16S[k] = f2b(v);
    }

    // B-frags: wave handles nt = wave*3 .. wave*3+2
    bf16x8 bfr[3][3];
    #pragma unroll
    for (int tnt = 0; tnt < 3; ++tnt) {
        const int i = (wave * 3 + tnt) * 16 + lm;  // M-row index (output n)
        const bool v = (i < 95);
        const float* br = cvismat_w + (size_t)c * 9025 + (size_t)(v ? i : 0) * 95;
        #pragma unroll
        for (int ks = 0; ks < 3; ++ks) {
            f32x4 lo = {0,0,0,0}, hi = {0,0,0,0};
            if (v) {
                if (ks < 2 || quad < 3) {
                    lo = ld4u(br + ks * 32 + quad * 8);
                    hi = ld4u(br + ks * 32 + quad * 8 + 4);
                } else {                          // j = 88..95 (95 = pad)
                    lo = ld4u(br + 88);
                    hi.x = br[92]; hi.y = br[93]; hi.z = br[94]; hi.w = 0.f;
                }
            }
            bfr[tnt][ks] = cvt8(lo, hi);
        }
    }

    for (int m0 = 0; m0 < n; m0 += 16) {
        // A-frags: gathered p0G rows (aligned; col 95 pre-zeroed)
        const int am = m0 + lm;
        const int ab = bins[c * CAP + (am < n ? am : 0)];
        const float* pr = p0G + (size_t)ab * 96 + quad * 8;
        bf16x8 a[3];
        #pragma unroll
        for (int ks = 0; ks < 3; ++ks)
            a[ks] = cvt8(*(const f32x4*)(pr + ks * 32),
                         *(const f32x4*)(pr + ks * 32 + 4));
        f32x4 acc[3] = {{0,0,0,0}, {0,0,0,0}, {0,0,0,0}};
        #pragma unroll
        for (int tnt = 0; tnt < 3; ++tnt)
            #pragma unroll
            for (int ks = 0; ks < 3; ++ks)
                acc[tnt] = __builtin_amdgcn_mfma_f32_16x16x32_bf16(
                    a[ks], bfr[tnt][ks], acc[tnt], 0, 0, 0);

        __syncthreads();                 // prior chunk consumed; biases ready
        if (tid < 16) brS[tid] = bins[c * CAP + ((m0 + tid < n) ? m0 + tid : 0)];
        #pragma unroll
        for (int tnt = 0; tnt < 3; ++tnt) {
            const int i = (wave * 3 + tnt) * 16 + lm;
            #pragma unroll
            for (int r = 0; r < 4; ++r)
                qS[(quad * 4 + r) * 96 + i] = acc[tnt][r] + cvbS[i];
        }
        __syncthreads();

        // s[b] = dot(itmq, cbb): 8 lanes/row
        {
            const int rr = tid >> 3, q8 = tid & 7;
            float p = 0.f;
            if (m0 + rr < n)
                for (int i = q8; i < 95; i += 8) p += qS[rr * 96 + i] * cbbS[i];
            p += __shfl_xor(p, 4, 8);
            p += __shfl_xor(p, 2, 8);
            p += __shfl_xor(p, 1, 8);
            if (q8 == 0 && m0 + rr < n) s_out[brS[rr]] = p;
        }
        // X tail: cols 33..127 itmq, 161..255 cbb
        const int nv = min(16, n - m0);
        for (int idx = tid; idx < nv * 95; idx += 128) {
            int r2 = idx / 95;
            int col = idx - r2 * 95;
            int bb = brS[r2];
            XA[xa_addr(bb, 33 + col)] = f2b(qS[r2 * 96 + col]);
            XA[xa_addr(bb, 161 + col)] = cbb16S[col];
        }
    }
}

// ---------------- Kernel 5: GEMM out = X @ W^T + s + t — no LDS -----------
__global__ __launch_bounds__(256) void gemm_kernel(
    const u16* __restrict__ XA, const u16* __restrict__ WB,
    const float* __restrict__ s, const float* __restrict__ t,
    float* __restrict__ out)
{
    const int tid = threadIdx.x;
    const int wave = tid >> 6;
    const int lane = tid & 63;
    const int lm = lane & 15;
    const int quad = lane >> 4;
    const int lofs = quad * 128 + lm * 8;

    const int mb = blockIdx.x * 4 + wave;
    const u16* abase = XA + (size_t)mb * 4096;
    const u16* wb0 = WB + (size_t)(blockIdx.y * 4 + 0) * 4096;
    const u16* wb1 = WB + (size_t)(blockIdx.y * 4 + 1) * 4096;
    const u16* wb2 = WB + (size_t)(blockIdx.y * 4 + 2) * 4096;
    const u16* wb3 = WB + (size_t)(blockIdx.y * 4 + 3) * 4096;

    f32x4 acc0 = {0.f, 0.f, 0.f, 0.f};
    f32x4 acc1 = {0.f, 0.f, 0.f, 0.f};
    f32x4 acc2 = {0.f, 0.f, 0.f, 0.f};
    f32x4 acc3 = {0.f, 0.f, 0.f, 0.f};

    #pragma unroll 2
    for (int ks = 0; ks < 8; ++ks) {
        const int o = ks * 512 + lofs;
        bf16x8 a = __builtin_bit_cast(bf16x8, *(const u16x8*)(abase + o));
        bf16x8 b0 = __builtin_bit_cast(bf16x8, *(const u16x8*)(wb0 + o));
        bf16x8 b1 = __builtin_bit_cast(bf16x8, *(const u16x8*)(wb1 + o));
        bf16x8 b2 = __builtin_bit_cast(bf16x8, *(const u16x8*)(wb2 + o));
        bf16x8 b3 = __builtin_bit_cast(bf16x8, *(const u16x8*)(wb3 + o));
        acc0 = __builtin_amdgcn_mfma_f32_16x16x32_bf16(a, b0, acc0, 0, 0, 0);
        acc1 = __builtin_amdgcn_mfma_f32_16x16x32_bf16(a, b1, acc1, 0, 0, 0);
        acc2 = __builtin_amdgcn_mfma_f32_16x16x32_bf16(a, b2, acc2, 0, 0, 0);
        acc3 = __builtin_amdgcn_mfma_f32_16x16x32_bf16(a, b3, acc3, 0, 0, 0);
    }

    const int m0 = mb * 16;
    float sv[4];
    #pragma unroll
    for (int r = 0; r < 4; ++r) sv[r] = s[m0 + quad * 4 + r];

    f32x4 accs[4] = {acc0, acc1, acc2, acc3};
    #pragma unroll
    for (int nf = 0; nf < 4; ++nf) {
        int u = blockIdx.y * 64 + nf * 16 + lm;
        if (u < USER_N) {
            float tv = t[u];
            #pragma unroll
            for (int r = 0; r < 4; ++r) {
                int ob = m0 + quad * 4 + r;
                out[(size_t)ob * USER_N + u] = accs[nf][r] + sv[r] + tv;
            }
        }
    }
}

extern "C" void kernel_launch(void* const* d_in, const int* in_sizes, int n_in,
                              void* d_out, int out_size, void* d_ws, size_t ws_size,
                              hipStream_t stream) {
    const float* feat      = (const float*)d_in[0];
    const int*   fcat      = (const int*)d_in[1];
    // d_in[2] fusr, d_in[3] fitm, d_in[4] flg: unused (flg==1 branch)
    const float* usr_w     = (const float*)d_in[5];
    const float* cate_w    = (const float*)d_in[6];
    const float* cmat_w    = (const float*)d_in[7];
    const float* cbias_w   = (const float*)d_in[8];
    const float* ubias_w   = (const float*)d_in[9];
    const float* cbiasb_w  = (const float*)d_in[10];
    const float* fc0_w     = (const float*)d_in[11];
    const float* fc0_b     = (const float*)d_in[12];
    const float* cvismat_w = (const float*)d_in[13];
    const float* cvisbias_w= (const float*)d_in[14];
    float* out = (float*)d_out;

    char* ws = (char*)d_ws;
    u16*   XA     = (u16*)(ws);                 // 4,194,304 B
    u16*   WB     = (u16*)(ws + 4194304);       //   524,288 B
    float* s      = (float*)(ws + 4718592);     //    32,768 B
    float* t      = (float*)(ws + 4751360);     //     4,096 B
    int*   counts = (int*)(ws + 4755456);       //     5,600 B
    int*   bins   = (int*)(ws + 4761056);       //   358,400 B
    float* p0G    = (float*)(ws + 5119456);     // 3,145,728 B

    pack_kernel<<<128, 256, 0, stream>>>(usr_w, ubias_w, WB, t, counts);
    bin_kernel<<<32, 256, 0, stream>>>(fcat, counts, bins);
    p0chain_kernel<<<256, 128, 0, stream>>>(feat, fcat, cate_w, cmat_w,
                                            cbias_w, fc0_w, fc0_b, p0G, XA);
    itmq_kernel<<<CATE_N, 128, 0, stream>>>(cvismat_w, cvisbias_w, cbiasb_w,
                                            counts, bins, p0G, XA, s);
    gemm_kernel<<<dim3(128, 16), 256, 0, stream>>>(XA, WB, s, t, out);
}